// Round 6
// baseline (246.885 us; speedup 1.0000x reference)
//
#include <hip/hip_runtime.h>
#include <hip/hip_bf16.h>

#define NUM_SLOTS 168
#define NUM_CATS 2048
#define BATCH 512
#define SEQ 200
#define NROWS (BATCH * SEQ)          // 102,400
#define CHUNK 100                     // rows per gather block; 1024 blocks exact

// Native clang vector type — __builtin_nontemporal_store requires a vector of
// scalars, not HIP's HIP_vector_type class.
typedef float v4f __attribute__((ext_vector_type(4)));

// ---- workspace layout (int/float slots) ----
// [0, 344064)            probs: 168*2048 f32
// [344064, 344232)       counts: 168 int
// [344408, 344576)       cursors: 168 int
// [344576, 446976)       sorted: 102,400 int (packed (h<<17)|row)
#define WS_PROBS 0
#define WS_COUNTS 344064
#define WS_CURSORS 344408
#define WS_SORTED 344576

// Kernel 1: row-wise softmax of the [168, 2048] matrix into workspace.
// Block 0 also zeroes the histogram counters (runs before count_kernel).
__global__ void softmax_rows_kernel(const float* __restrict__ mat,
                                    float* __restrict__ probs,
                                    int* __restrict__ counts) {
    const int row = blockIdx.x;
    const int t = threadIdx.x;
    if (row == 0 && t < NUM_SLOTS) counts[t] = 0;

    const float* r = mat + row * NUM_CATS;
    float* o = probs + row * NUM_CATS;

    float vals[8];
    float mx = -INFINITY;
#pragma unroll
    for (int j = 0; j < 8; ++j) {
        vals[j] = r[t + j * 256];
        mx = fmaxf(mx, vals[j]);
    }
#pragma unroll
    for (int off = 32; off >= 1; off >>= 1) mx = fmaxf(mx, __shfl_xor(mx, off));

    __shared__ float redmax[4];
    __shared__ float redsum[4];
    const int wave = t >> 6;
    if ((t & 63) == 0) redmax[wave] = mx;
    __syncthreads();
    mx = fmaxf(fmaxf(redmax[0], redmax[1]), fmaxf(redmax[2], redmax[3]));

    float sum = 0.0f;
#pragma unroll
    for (int j = 0; j < 8; ++j) {
        vals[j] = expf(vals[j] - mx);
        sum += vals[j];
    }
#pragma unroll
    for (int off = 32; off >= 1; off >>= 1) sum += __shfl_xor(sum, off);
    if ((t & 63) == 0) redsum[wave] = sum;
    __syncthreads();
    sum = redsum[0] + redsum[1] + redsum[2] + redsum[3];

    const float inv = 1.0f / sum;
#pragma unroll
    for (int j = 0; j < 8; ++j) o[t + j * 256] = vals[j] * inv;
}

// Kernel 2: per-block LDS histogram of hour values -> global counts.
// 100 blocks x 256 threads x 4 rows = 102,400.
__global__ void __launch_bounds__(256) count_kernel(const int* __restrict__ hours,
                                                    int* __restrict__ counts) {
    __shared__ int hist[NUM_SLOTS];
    const int t = threadIdx.x;
    if (t < NUM_SLOTS) hist[t] = 0;
    __syncthreads();
    const int base = blockIdx.x * 1024 + t;
#pragma unroll
    for (int k = 0; k < 4; ++k) atomicAdd(&hist[hours[base + k * 256]], 1);
    __syncthreads();
    if (t < NUM_SLOTS) atomicAdd(&counts[t], hist[t]);
}

// Kernel 3: exclusive prefix sum of 168 counts -> cursors. One block.
__global__ void __launch_bounds__(256) prefix_kernel(const int* __restrict__ counts,
                                                     int* __restrict__ cursors) {
    __shared__ int c[NUM_SLOTS];
    const int t = threadIdx.x;
    if (t < NUM_SLOTS) c[t] = counts[t];
    __syncthreads();
    if (t == 0) {
        int s = 0;
        for (int i = 0; i < NUM_SLOTS; ++i) { const int v = c[i]; c[i] = s; s += v; }
    }
    __syncthreads();
    if (t < NUM_SLOTS) cursors[t] = c[t];
}

// Kernel 4: scatter rows into hour-buckets. Order within a bucket is
// nondeterministic (atomics) but the final OUTPUT is identical regardless —
// each row is written exactly once with its hour's probs row.
// Packed entry: (h<<17)|row  (row < 2^17, h < 168).
__global__ void __launch_bounds__(256) scatter_kernel(const int* __restrict__ hours,
                                                      int* __restrict__ cursors,
                                                      int* __restrict__ sorted) {
    const int i = blockIdx.x * 256 + threadIdx.x;   // grid 400 -> 102,400
    const int h = hours[i];
    const int pos = atomicAdd(&cursors[h], 1);
    sorted[pos] = (h << 17) | i;
}

// Kernel 5: gather with register-resident source. Each block walks CHUNK
// entries of the hour-sorted list (staged in LDS -> lgkmcnt only, no VMEM
// coupling). The probs row is reloaded into registers only when the hour
// changes (~1-2x per chunk); otherwise the loop is a pure back-to-back
// nt-store stream with ZERO vmcnt waits — structurally identical to a fill.
__global__ void __launch_bounds__(256)
gather_bucketed_kernel(const int* __restrict__ sorted,
                       const v4f* __restrict__ probs,
                       v4f* __restrict__ out) {
    __shared__ int lst[CHUNK];
    const int t = threadIdx.x;
    const int base = blockIdx.x * CHUNK;
    if (t < CHUNK) lst[t] = sorted[base + t];
    __syncthreads();

    int cur_h = -1;
    v4f a, b;
    for (int i = 0; i < CHUNK; ++i) {
        const int v = lst[i];                // LDS broadcast read
        const int h = v >> 17;
        const int row = v & 0x1FFFF;
        if (h != cur_h) {                    // block-uniform, rare
            a = probs[(h << 9) + t];
            b = probs[(h << 9) + t + 256];
            cur_h = h;
        }
        v4f* __restrict__ dst = out + ((size_t)row << 9);
        __builtin_nontemporal_store(a, &dst[t]);
        __builtin_nontemporal_store(b, &dst[t + 256]);
    }
}

extern "C" void kernel_launch(void* const* d_in, const int* in_sizes, int n_in,
                              void* d_out, int out_size, void* d_ws, size_t ws_size,
                              hipStream_t stream) {
    const int* inputs_hour = (const int*)d_in[0];            // [512, 200] int32
    const float* catid_time_matrix = (const float*)d_in[1];  // [168, 2048] f32
    float* out = (float*)d_out;                               // [512, 200, 2048] f32

    float* probs = (float*)d_ws + WS_PROBS;
    int* counts = (int*)d_ws + WS_COUNTS;
    int* cursors = (int*)d_ws + WS_CURSORS;
    int* sorted = (int*)d_ws + WS_SORTED;

    // 1: softmax (+ zero counts)
    softmax_rows_kernel<<<NUM_SLOTS, 256, 0, stream>>>(catid_time_matrix, probs, counts);
    // 2: histogram
    count_kernel<<<NROWS / 1024, 256, 0, stream>>>(inputs_hour, counts);
    // 3: prefix -> cursors
    prefix_kernel<<<1, 256, 0, stream>>>(counts, cursors);
    // 4: scatter packed (h,row) into buckets
    scatter_kernel<<<NROWS / 256, 256, 0, stream>>>(inputs_hour, cursors, sorted);
    // 5: gather — pure store stream
    gather_bucketed_kernel<<<NROWS / CHUNK, 256, 0, stream>>>(
        sorted, (const v4f*)probs, (v4f*)out);
}

// Round 7
// 175.062 us; speedup vs baseline: 1.4103x; 1.4103x over previous
//
#include <hip/hip_runtime.h>
#include <hip/hip_bf16.h>

#define NUM_SLOTS 168
#define NUM_CATS 2048
#define BATCH 512
#define SEQ 200
#define NROWS (BATCH * SEQ)   // 102,400
#define C 8                    // rows per burst block; 12,800 blocks exact

// Native clang vector type — __builtin_nontemporal_store requires a vector of
// scalars, not HIP's HIP_vector_type class.
typedef float v4f __attribute__((ext_vector_type(4)));

// Kernel 1: row-wise softmax of the [168, 2048] matrix into workspace.
// One block (256 threads) per row; each thread owns 8 elements.
__global__ void softmax_rows_kernel(const float* __restrict__ mat,
                                    float* __restrict__ probs) {
    const int row = blockIdx.x;
    const int t = threadIdx.x;
    const float* r = mat + row * NUM_CATS;
    float* o = probs + row * NUM_CATS;

    float vals[8];
    float mx = -INFINITY;
#pragma unroll
    for (int j = 0; j < 8; ++j) {
        vals[j] = r[t + j * 256];
        mx = fmaxf(mx, vals[j]);
    }
#pragma unroll
    for (int off = 32; off >= 1; off >>= 1) mx = fmaxf(mx, __shfl_xor(mx, off));

    __shared__ float redmax[4];
    __shared__ float redsum[4];
    const int wave = t >> 6;
    if ((t & 63) == 0) redmax[wave] = mx;
    __syncthreads();
    mx = fmaxf(fmaxf(redmax[0], redmax[1]), fmaxf(redmax[2], redmax[3]));

    float sum = 0.0f;
#pragma unroll
    for (int j = 0; j < 8; ++j) {
        vals[j] = expf(vals[j] - mx);
        sum += vals[j];
    }
#pragma unroll
    for (int off = 32; off >= 1; off >>= 1) sum += __shfl_xor(sum, off);
    if ((t & 63) == 0) redsum[wave] = sum;
    __syncthreads();
    sum = redsum[0] + redsum[1] + redsum[2] + redsum[3];

    const float inv = 1.0f / sum;
#pragma unroll
    for (int j = 0; j < 8; ++j) o[t + j * 256] = vals[j] * inv;
}

// Kernel 2: block-terminated burst gather. Each block owns 8 CONTIGUOUS output
// rows (64 KB dst). Fully unrolled straight-line body: 8 uniform s_loads of
// hours -> 16 independent dwordx4 loads into 16 distinct register pairs ->
// 16 nt stores -> endpgm. No register reuse after the stores means the
// compiler emits NO trailing vmcnt waits: stores pile to vmcnt depth and
// drain in the background after the wave terminates, while the CP dispatches
// fresh blocks. This removes the per-row store-drain round-trip that capped
// every loop-carried variant at ~4.9 TB/s.
__global__ void __launch_bounds__(256)
gather_burst_kernel(const int* __restrict__ hours,
                    const v4f* __restrict__ probs,
                    v4f* __restrict__ out) {
    const int t = threadIdx.x;                  // 0..255
    const int row0 = blockIdx.x * C;

    int h[C];
#pragma unroll
    for (int r = 0; r < C; ++r) h[r] = hours[row0 + r];   // uniform -> s_load

    v4f a[C], b[C];
#pragma unroll
    for (int r = 0; r < C; ++r) {               // 16 independent vector loads
        a[r] = probs[(h[r] << 9) + t];
        b[r] = probs[(h[r] << 9) + t + 256];
    }
#pragma unroll
    for (int r = 0; r < C; ++r) {               // 16 back-to-back nt stores
        v4f* __restrict__ dst = out + ((size_t)(row0 + r) << 9);
        __builtin_nontemporal_store(a[r], &dst[t]);
        __builtin_nontemporal_store(b[r], &dst[t + 256]);
    }
}

extern "C" void kernel_launch(void* const* d_in, const int* in_sizes, int n_in,
                              void* d_out, int out_size, void* d_ws, size_t ws_size,
                              hipStream_t stream) {
    const int* inputs_hour = (const int*)d_in[0];            // [512, 200] int32
    const float* catid_time_matrix = (const float*)d_in[1];  // [168, 2048] f32
    float* out = (float*)d_out;                               // [512, 200, 2048] f32
    float* probs = (float*)d_ws;                              // 168*2048 f32

    // 1: softmax (tiny)
    softmax_rows_kernel<<<NUM_SLOTS, 256, 0, stream>>>(catid_time_matrix, probs);

    // 2: burst gather — 12,800 terminating blocks, contiguous 64 KB dst each
    gather_burst_kernel<<<NROWS / C, 256, 0, stream>>>(
        inputs_hour, (const v4f*)probs, (v4f*)out);
}